// Round 4
// baseline (354.892 us; speedup 1.0000x reference)
//
#include <hip/hip_runtime.h>
#include <hip/hip_bf16.h>

// Problem constants
#define BB 8
#define EE 16
#define NN 262144          // H*W = 512*512
#define KK 32
#define DELTA_VAR 0.5f
#define TWO_DELTA_DIST 3.0f
#define GAMMA_REG 0.001f

#define P1 1024            // pixels per block, kernel 1
#define TILE 512           // pixels per LDS tile, kernel 2
#define ITERS2 4           // tiles per block, kernel 2

// ---------------------------------------------------------------------------
// Kernel 1: per-(b,k) pixel counts and per-(b,k,e) embedding sums.
// Thread layout: e = t>>4, sub = t&15. Each thread scatters into a private
// LDS histogram priv[t*33 + k] (pad 33 -> bank (t+k)%32, no conflicts, no
// atomics). Block-level reduce, then global atomicAdd.
// ---------------------------------------------------------------------------
__global__ __launch_bounds__(256) void k1_sums(const float* __restrict__ emb,
                                               const int* __restrict__ mask,
                                               float* __restrict__ g_sums,
                                               float* __restrict__ g_cnt) {
    __shared__ float priv[256 * 33];
    __shared__ float cpriv[16 * 33];
    const int t = threadIdx.x;
    const int b = blockIdx.y;
    const int e = t >> 4, sub = t & 15;

    for (int i = t; i < 256 * 33; i += 256) priv[i] = 0.0f;
    for (int i = t; i < 16 * 33; i += 256) cpriv[i] = 0.0f;
    __syncthreads();

    const int n0 = blockIdx.x * P1;
    const float4* ep = (const float4*)(emb + ((size_t)b * EE + e) * NN + n0);
    const int4*   mp = (const int4*)(mask + (size_t)b * NN + n0);
    float* pp = &priv[t * 33];

    for (int i = 0; i < P1 / 64; i++) {
        float4 v  = ep[i * 16 + sub];
        int4   l4 = mp[i * 16 + sub];
        int   ks[4] = {l4.x, l4.y, l4.z, l4.w};
        float vs[4] = {v.x, v.y, v.z, v.w};
        #pragma unroll
        for (int j = 0; j < 4; j++) {
            int k = ks[j];
            if (k > 0) {
                pp[k - 1] += vs[j];
                if (e == 0) cpriv[sub * 33 + (k - 1)] += 1.0f;
            }
        }
    }
    __syncthreads();

    // reduce over the 16 sub-threads of each e
    for (int idx = t; idx < KK * EE; idx += 256) {
        int k = idx & 31, ee = idx >> 5;
        float s = 0.0f;
        #pragma unroll
        for (int s2 = 0; s2 < 16; s2++) s += priv[(ee * 16 + s2) * 33 + k];
        atomicAdd(&g_sums[((size_t)b * KK + k) * EE + ee], s);
    }
    if (t < KK) {
        float s = 0.0f;
        #pragma unroll
        for (int s2 = 0; s2 < 16; s2++) s += cpriv[s2 * 33 + t];
        atomicAdd(&g_cnt[b * KK + t], s);
    }
}

// ---------------------------------------------------------------------------
// Kernel 2: variance-term accumulation. Stage [16][TILE] embedding tile in
// LDS; each thread handles whole pixels. Centers in LDS padded x17 so that
// distinct labels hit distinct banks (17k mod 32 bijective), equal labels
// broadcast -> conflict-free scalar reads.
// ---------------------------------------------------------------------------
__global__ __launch_bounds__(256) void k2_var(const float* __restrict__ emb,
                                              const int* __restrict__ mask,
                                              const float* __restrict__ g_sums,
                                              const float* __restrict__ g_cnt,
                                              float* __restrict__ g_var) {
    __shared__ float tile[EE][TILE];
    __shared__ float c_lds[KK * 17];
    __shared__ int   lab[TILE];
    __shared__ float whist[4][KK];
    const int t = threadIdx.x;
    const int b = blockIdx.y;

    // centers for this batch
    for (int idx = t; idx < KK * EE; idx += 256) {
        int k = idx >> 4, e = idx & 15;
        float cnt = g_cnt[b * KK + k];
        c_lds[k * 17 + e] = g_sums[((size_t)b * KK + k) * EE + e] / fmaxf(cnt, 1.0f);
    }
    if (t < 4 * KK) ((float*)whist)[t] = 0.0f;
    __syncthreads();

    const float4* ef = (const float4*)(emb + (size_t)b * EE * NN);

    for (int it = 0; it < ITERS2; it++) {
        const int n0 = (blockIdx.x * ITERS2 + it) * TILE;
        // stage tile: 16 rows x 512 floats = 2048 float4, 8 per thread
        #pragma unroll
        for (int r = 0; r < 8; r++) {
            int idx = r * 256 + t;
            int e = idx >> 7;        // TILE/4 = 128 float4 per row
            int off = idx & 127;
            float4 v = ef[(size_t)e * (NN / 4) + (n0 / 4) + off];
            *((float4*)&tile[e][off * 4]) = v;
        }
        if (t < TILE / 4) {
            ((int4*)lab)[t] = ((const int4*)(mask + (size_t)b * NN + n0))[t];
        }
        __syncthreads();

        #pragma unroll
        for (int p = 0; p < TILE / 256; p++) {
            int j = t + p * 256;
            int k = lab[j];
            if (k > 0) {
                int kk = k - 1;
                float sq = 0.0f;
                #pragma unroll
                for (int e = 0; e < EE; e++) {
                    float d = tile[e][j] - c_lds[kk * 17 + e];
                    sq += d * d;
                }
                float dd = sqrtf(sq);
                float h = fmaxf(dd - DELTA_VAR, 0.0f);
                atomicAdd(&whist[t >> 6][kk], h * h);
            }
        }
        __syncthreads();
    }

    if (t < KK) {
        float s = whist[0][t] + whist[1][t] + whist[2][t] + whist[3][t];
        atomicAdd(&g_var[b * KK + t], s);
    }
}

// ---------------------------------------------------------------------------
// Kernel 3: finalize. One block, thread (b = t>>5, k = t&31).
// ---------------------------------------------------------------------------
__global__ __launch_bounds__(256) void k3_final(const float* __restrict__ g_sums,
                                                const float* __restrict__ g_cnt,
                                                const float* __restrict__ g_var,
                                                float* __restrict__ out) {
    __shared__ float cen[BB][KK][EE];
    __shared__ float pres[BB][KK];
    __shared__ float red[BB][4];
    const int t = threadIdx.x;
    const int b = t >> 5, k = t & 31;

    float cnt = g_cnt[b * KK + k];
    float sc = fmaxf(cnt, 1.0f);
    float c2 = 0.0f;
    #pragma unroll
    for (int e = 0; e < EE; e++) {
        float c = g_sums[((size_t)b * KK + k) * EE + e] / sc;
        cen[b][k][e] = c;
        c2 += c * c;
    }
    float presf = (cnt > 0.0f) ? 1.0f : 0.0f;
    pres[b][k] = presf;
    float per_inst = g_var[b * KK + k] / sc;
    float cn = presf * sqrtf(c2);
    __syncthreads();

    float hp = 0.0f;
    if (presf > 0.0f) {
        for (int j = k + 1; j < KK; j++) {
            if (pres[b][j] > 0.0f) {
                float dsq = 0.0f;
                #pragma unroll
                for (int e = 0; e < EE; e++) {
                    float d = cen[b][k][e] - cen[b][j][e];
                    dsq += d * d;
                }
                float dd = sqrtf(dsq);
                float h = fmaxf(TWO_DELTA_DIST - dd, 0.0f);
                hp += h * h;
            }
        }
    }

    // reduce across the 32 k-lanes of each batch
    float v0 = per_inst, v1 = hp, v2 = cn, v3 = presf;
    #pragma unroll
    for (int off = 16; off > 0; off >>= 1) {
        v0 += __shfl_down(v0, off, 32);
        v1 += __shfl_down(v1, off, 32);
        v2 += __shfl_down(v2, off, 32);
        v3 += __shfl_down(v3, off, 32);
    }
    if (k == 0) {
        float n_inst = v3;
        float validf = (n_inst > 0.0f) ? 1.0f : 0.0f;
        float safe_n = fmaxf(n_inst, 1.0f);
        float lv = v0 / safe_n;
        float npairs = n_inst * (n_inst - 1.0f) * 0.5f;
        float ld = v1 / fmaxf(npairs, 1.0f);
        float lr = v2 / safe_n;
        red[b][0] = lv * validf;
        red[b][1] = ld * validf;
        red[b][2] = lr * validf;
        red[b][3] = validf;
    }
    __syncthreads();
    if (t == 0) {
        float sv = 0, sd = 0, sr = 0, vb = 0;
        for (int b2 = 0; b2 < BB; b2++) {
            sv += red[b2][0]; sd += red[b2][1]; sr += red[b2][2]; vb += red[b2][3];
        }
        vb = fmaxf(vb, 1.0f);
        float L_var = sv / vb, L_dist = sd / vb, L_reg = sr / vb;
        out[0] = L_var + L_dist + GAMMA_REG * L_reg;
        out[1] = L_var;
        out[2] = L_dist;
        out[3] = L_reg;
    }
}

extern "C" void kernel_launch(void* const* d_in, const int* in_sizes, int n_in,
                              void* d_out, int out_size, void* d_ws, size_t ws_size,
                              hipStream_t stream) {
    const float* emb  = (const float*)d_in[0];
    const int*   mask = (const int*)d_in[1];
    float* out = (float*)d_out;
    float* ws  = (float*)d_ws;

    float* g_sums = ws;                 // B*K*E = 4096 floats
    float* g_cnt  = ws + BB * KK * EE;  // 256 floats
    float* g_var  = g_cnt + BB * KK;    // 256 floats

    hipMemsetAsync(d_ws, 0, (BB * KK * EE + 2 * BB * KK) * sizeof(float), stream);

    dim3 blk(256);
    dim3 g1(NN / P1, BB);               // (256, 8)
    k1_sums<<<g1, blk, 0, stream>>>(emb, mask, g_sums, g_cnt);

    dim3 g2(NN / (TILE * ITERS2), BB);  // (128, 8)
    k2_var<<<g2, blk, 0, stream>>>(emb, mask, g_sums, g_cnt, g_var);

    k3_final<<<dim3(1), blk, 0, stream>>>(g_sums, g_cnt, g_var, out);
}